// Round 14
// baseline (1001.163 us; speedup 1.0000x reference)
//
#include <hip/hip_runtime.h>

typedef __attribute__((ext_vector_type(8))) _Float16 f16x8;
typedef __attribute__((ext_vector_type(4))) float f32x4;

#define B_    1024
#define C_    512
#define NCODE 2048
#define NTOT  (B_ * 64 * C_)   // 33,554,432
#define BN_   (B_ * 64)        // 65,536
#define DELTA 6e-3f

__device__ __forceinline__ float wseg(int k) {
    return k < 256 ? (1.0f / 256.0f) : (k < 384 ? (1.0f / 128.0f) : (1.0f / 64.0f));
}

// sortable-key helpers: ascending float -> ascending uint; low 11 bits replaced by code idx
__device__ __forceinline__ unsigned packkey(float s, int code) {
    unsigned u = __float_as_uint(s);
    u = (u & 0x80000000u) ? ~u : (u | 0x80000000u);
    return (u & 0xFFFFF800u) | (unsigned)code;
}
__device__ __forceinline__ float unpk(unsigned k) {
    unsigned us = k & 0xFFFFF800u;
    return (us & 0x80000000u) ? __uint_as_float(us ^ 0x80000000u) : __uint_as_float(~us);
}

// ---------------- E = base @ W^T  (+ fused f16 weighted copy) ----------------
__global__ __launch_bounds__(256) void k_gemm_e(const float* __restrict__ A,
                                                const float* __restrict__ Bm,
                                                float* __restrict__ E,
                                                _Float16* __restrict__ wk) {
    __shared__ float As[16][68];
    __shared__ float Bs[16][68];
    int tid = threadIdx.x;
    int m0 = blockIdx.x * 64, n0 = blockIdx.y * 64;
    float acc[4][4] = {};
    int tx = tid & 15, ty = tid >> 4;
    int kk = tid & 15, rr = tid >> 4;
    for (int k0 = 0; k0 < 512; k0 += 16) {
        #pragma unroll
        for (int i = 0; i < 4; ++i) {
            As[kk][rr + i * 16] = A[(m0 + rr + i * 16) * 512 + k0 + kk];
            Bs[kk][rr + i * 16] = Bm[(n0 + rr + i * 16) * 512 + k0 + kk];
        }
        __syncthreads();
        #pragma unroll
        for (int k = 0; k < 16; ++k) {
            float4 a = *(const float4*)&As[k][ty * 4];
            float4 b = *(const float4*)&Bs[k][tx * 4];
            #pragma unroll
            for (int i = 0; i < 4; ++i) {
                float av = ((const float*)&a)[i];
                acc[i][0] = fmaf(av, b.x, acc[i][0]);
                acc[i][1] = fmaf(av, b.y, acc[i][1]);
                acc[i][2] = fmaf(av, b.z, acc[i][2]);
                acc[i][3] = fmaf(av, b.w, acc[i][3]);
            }
        }
        __syncthreads();
    }
    #pragma unroll
    for (int i = 0; i < 4; ++i)
        #pragma unroll
        for (int j = 0; j < 4; ++j) {
            int cc = m0 + ty * 4 + i;       // code index
            int kx = n0 + tx * 4 + j;       // k index
            float v = acc[i][j];
            E[cc * 512 + kx] = v;
            wk[cc * 512 + kx] = (_Float16)(v * wseg(kx));   // w = 2^-s, exact scale
        }
}

// ---------------- enorm[c] = sum_k wseg(k)*E[c][k]^2 ----------------
__global__ void k_enorm(const float* __restrict__ E, float* __restrict__ enorm) {
    int c = blockIdx.x * 256 + threadIdx.x;   // 2048
    float s = 0.0f;
    for (int k = 0; k < 512; ++k) {
        float v = E[c * 512 + k];
        s = fmaf(wseg(k) * v, v, s);
    }
    enorm[c] = s;
}

// ---------------- initial downsample (pn=1): q = mean_n f ----------------
__global__ __launch_bounds__(256) void k_down0(const float* __restrict__ f,
                                               _Float16* __restrict__ q16,
                                               float* __restrict__ qf) {
    int b = blockIdx.x, t = threadIdx.x;
    const float* src = f + (size_t)b * 64 * 512;
    float s0 = 0.f, s1 = 0.f;
    for (int n = 0; n < 64; ++n) {
        s0 += src[n * 512 + t];
        s1 += src[n * 512 + t + 256];
    }
    s0 *= (1.0f / 64.0f); s1 *= (1.0f / 64.0f);
    q16[(size_t)b * 512 + t] = (_Float16)s0;
    q16[(size_t)b * 512 + t + 256] = (_Float16)s1;
    qf[(size_t)b * 512 + t] = s0;
    qf[(size_t)b * 512 + t + 256] = s1;
}

// ================= 256x256 MFMA score kernel, 2x32KB buffers, 2 blocks/CU =================
// score[m][n] = enorm[n] - 2 * sum_k q16[m][k]*wek[n][k]
// Buf (32KB): [A rows0-127][A rows128-255][B 0-127][B 128-255], packed-XOR regions.
// T3-minimum staging: stage(t+1) issued right after tile-t's vmcnt(0)+barrier into
// the OTHER buffer (its readers completed before this barrier). 64KB LDS -> 2 blocks/CU
// so independent blocks cross-cover the per-tile latency.
#define GLL2(gp, loff) __builtin_amdgcn_global_load_lds( \
    (const __attribute__((address_space(1))) unsigned int*)(gp), \
    (__attribute__((address_space(3))) unsigned int*)(smem + (loff)), 16, 0, 0)

__global__ __launch_bounds__(512, 2) void k_score_256(
        const _Float16* __restrict__ q16, const _Float16* __restrict__ wek,
        const float* __restrict__ enorm, uint2* __restrict__ partial) {
    extern __shared__ char smem[];     // 65536 B
    int tid = threadIdx.x;
    int x = blockIdx.x;
    int bx = (x >> 3) & 7;                       // 8 col tiles of 256
    int g  = (x & 7) + ((x >> 6) << 3);          // row-group, XCD-chunked
    int m0 = g * 256, n0 = bx * 256;

    int lane = tid & 63, wave = tid >> 6;
    int wm = wave >> 2, wn = wave & 3;
    int lx = lane & 15, cg = lane >> 4;

    // ---- staging precompute (cell -> logical row/chunk, bijective XOR) ----
    int r2s = tid >> 3, sl = tid & 7;
    int us = sl ^ (r2s & 7);
    int cs = us & 3;
    int rws = r2s + ((us >> 2) << 6);            // 0..127 within region rows
    const _Float16* srcA0 = q16 + (size_t)(m0 + rws) * 512 + cs * 8;
    const _Float16* srcA1 = q16 + (size_t)(m0 + 128 + rws) * 512 + cs * 8;
    const _Float16* srcB0 = wek + (size_t)(n0 + rws) * 512 + cs * 8;
    const _Float16* srcB1 = wek + (size_t)(n0 + 128 + rws) * 512 + cs * 8;

    #define STG_A2(BUF, KT) { \
        GLL2(srcA0 + (KT) * 32, (BUF) * 32768 + tid * 16); \
        GLL2(srcA1 + (KT) * 32, (BUF) * 32768 + 8192 + tid * 16); }
    #define STG_B2(BUF, KT) { \
        GLL2(srcB0 + (KT) * 32, (BUF) * 32768 + 16384 + tid * 16); \
        GLL2(srcB1 + (KT) * 32, (BUF) * 32768 + 24576 + tid * 16); }

    // ---- fragment read offsets (bytes within a 32KB buffer) ----
    int Aoff[8];
    #pragma unroll
    for (int fi = 0; fi < 8; ++fi) {
        int rA = fi * 16 + lx;                   // 0..127 within rh = wm
        Aoff[fi] = wm * 8192 + (rA & 63) * 128 +
                   (((((rA >> 6) & 1) << 2) + cg) ^ (rA & 7)) * 16;
    }
    int Boff[4];
    #pragma unroll
    for (int fj = 0; fj < 4; ++fj) {
        int br = wn * 64 + fj * 16 + lx;         // 0..255
        int rB = br & 127;
        Boff[fj] = 16384 + (br >> 7) * 8192 + (rB & 63) * 128 +
                   (((((rB >> 6) & 1) << 2) + cg) ^ (rB & 7)) * 16;
    }

    f32x4 acc[8][4];
    #pragma unroll
    for (int i = 0; i < 8; ++i)
        #pragma unroll
        for (int j = 0; j < 4; ++j)
            acc[i][j] = (f32x4){0.f, 0.f, 0.f, 0.f};

    #define MF(a, b, c) __builtin_amdgcn_mfma_f32_16x16x32_f16(a, b, c, 0, 0, 0)

    // ---- prologue: stage tile 0 ----
    STG_A2(0, 0); STG_B2(0, 0);

    // ---- K loop: 16 tiles; vmcnt(0)+barrier, stage next into other buffer, compute ----
    #pragma unroll
    for (int t = 0; t < 16; ++t) {
        const int buf = (t & 1) * 32768;
        asm volatile("s_waitcnt vmcnt(0)" ::: "memory");   // stage(t) landed
        __builtin_amdgcn_s_barrier();                      // for ALL waves
        __builtin_amdgcn_sched_barrier(0);
        if (t < 15) {                                      // stage next tile (other buf;
            STG_A2((t + 1) & 1, t + 1);                    //  its readers done pre-barrier)
            STG_B2((t + 1) & 1, t + 1);
        }
        f16x8 b0 = *(const f16x8*)(smem + buf + Boff[0]);
        f16x8 b1 = *(const f16x8*)(smem + buf + Boff[1]);
        f16x8 b2 = *(const f16x8*)(smem + buf + Boff[2]);
        f16x8 b3 = *(const f16x8*)(smem + buf + Boff[3]);
        f16x8 a0 = *(const f16x8*)(smem + buf + Aoff[0]);
        __builtin_amdgcn_s_setprio(1);
        acc[0][0] = MF(a0, b0, acc[0][0]); acc[0][1] = MF(a0, b1, acc[0][1]);
        acc[0][2] = MF(a0, b2, acc[0][2]); acc[0][3] = MF(a0, b3, acc[0][3]);
        f16x8 a1 = *(const f16x8*)(smem + buf + Aoff[1]);
        acc[1][0] = MF(a1, b0, acc[1][0]); acc[1][1] = MF(a1, b1, acc[1][1]);
        acc[1][2] = MF(a1, b2, acc[1][2]); acc[1][3] = MF(a1, b3, acc[1][3]);
        f16x8 a2 = *(const f16x8*)(smem + buf + Aoff[2]);
        acc[2][0] = MF(a2, b0, acc[2][0]); acc[2][1] = MF(a2, b1, acc[2][1]);
        acc[2][2] = MF(a2, b2, acc[2][2]); acc[2][3] = MF(a2, b3, acc[2][3]);
        f16x8 a3 = *(const f16x8*)(smem + buf + Aoff[3]);
        acc[3][0] = MF(a3, b0, acc[3][0]); acc[3][1] = MF(a3, b1, acc[3][1]);
        acc[3][2] = MF(a3, b2, acc[3][2]); acc[3][3] = MF(a3, b3, acc[3][3]);
        f16x8 a4 = *(const f16x8*)(smem + buf + Aoff[4]);
        acc[4][0] = MF(a4, b0, acc[4][0]); acc[4][1] = MF(a4, b1, acc[4][1]);
        acc[4][2] = MF(a4, b2, acc[4][2]); acc[4][3] = MF(a4, b3, acc[4][3]);
        f16x8 a5 = *(const f16x8*)(smem + buf + Aoff[5]);
        acc[5][0] = MF(a5, b0, acc[5][0]); acc[5][1] = MF(a5, b1, acc[5][1]);
        acc[5][2] = MF(a5, b2, acc[5][2]); acc[5][3] = MF(a5, b3, acc[5][3]);
        f16x8 a6 = *(const f16x8*)(smem + buf + Aoff[6]);
        acc[6][0] = MF(a6, b0, acc[6][0]); acc[6][1] = MF(a6, b1, acc[6][1]);
        acc[6][2] = MF(a6, b2, acc[6][2]); acc[6][3] = MF(a6, b3, acc[6][3]);
        f16x8 a7 = *(const f16x8*)(smem + buf + Aoff[7]);
        acc[7][0] = MF(a7, b0, acc[7][0]); acc[7][1] = MF(a7, b1, acc[7][1]);
        acc[7][2] = MF(a7, b2, acc[7][2]); acc[7][3] = MF(a7, b3, acc[7][3]);
        __builtin_amdgcn_s_setprio(0);
    }

    // ---- epilogue: two 512-task halves within 64KB ----
    float en[4];
    #pragma unroll
    for (int fj = 0; fj < 4; ++fj) en[fj] = enorm[n0 + wn * 64 + fj * 16 + lx];

    #pragma unroll
    for (int half = 0; half < 2; ++half) {
        __syncthreads();
        if (wm == half) {
            #pragma unroll
            for (int fi = 0; fi < 8; ++fi) {
                #pragma unroll
                for (int rr = 0; rr < 4; ++rr) {
                    unsigned a1 = 0xFFFFFFFFu, a2 = 0xFFFFFFFFu;
                    #pragma unroll
                    for (int fj = 0; fj < 4; ++fj) {
                        float s = fmaf(-2.0f, acc[fi][fj][rr], en[fj]);
                        unsigned key = packkey(s, n0 + wn * 64 + fj * 16 + lx);
                        if (key < a1) { a2 = a1; a1 = key; }
                        else if (key < a2) a2 = key;
                    }
                    int row_local = fi * 16 + cg * 4 + rr;     // 0..127 in this half
                    int task = row_local * 4 + wn;             // 0..511
                    *(uint2*)(smem + task * 128 + ((lx ^ (task & 15)) * 8)) =
                        make_uint2(a1, a2);
                }
            }
        }
        __syncthreads();
        {
            int task = tid;                                    // 512 tasks
            unsigned a1 = 0xFFFFFFFFu, a2 = 0xFFFFFFFFu;
            #pragma unroll
            for (int j = 0; j < 16; ++j) {
                uint2 pr = *(const uint2*)(smem + task * 128 + (((j ^ (task & 15))) * 8));
                if (pr.x < a1) { a2 = min(a1, pr.y); a1 = pr.x; }
                else a2 = min(a2, pr.x);
            }
            int row = m0 + half * 128 + (task >> 2);
            partial[(size_t)row * 32 + (bx * 4 + (task & 3))] = make_uint2(a1, a2);
        }
    }
    #undef STG_A2
    #undef STG_B2
    #undef MF
}

// ---------------- 128x128 score kernel (r6 structure; used for pn <= 4) ----------------
__global__ __launch_bounds__(256) void k_score_f16(
        const _Float16* __restrict__ q16, const _Float16* __restrict__ wek,
        const float* __restrict__ enorm, uint2* __restrict__ partial) {
    __shared__ __align__(16) char smem[37376];
    float*  ensh = (float*)(smem + 32768);
    float4* bb   = (float4*)(smem + 33280);

    int tid = threadIdx.x;
    int x = blockIdx.x;
    int bx = (x >> 3) & 15;
    int g  = (x & 7) + ((x >> 7) << 3);
    int m0 = g * 128, n0 = bx * 128;
    if (tid < 128) ensh[tid] = enorm[n0 + tid];

    int lane = tid & 63, wave = tid >> 6;
    int wrow = (wave & 1) * 64, wcol = (wave >> 1) * 64;
    int lx = lane & 15, cg = lane >> 4;

    int u = (tid & 7) ^ ((tid >> 3) & 7);
    int chunk = u & 3;
    int rhi = (u >> 2) << 6;
    int r0 = (tid >> 3) + rhi;
    int r1 = 32 + (tid >> 3) + rhi;
    const _Float16* gqa0 = q16 + (size_t)(m0 + r0) * 512 + chunk * 8;
    const _Float16* gqa1 = q16 + (size_t)(m0 + r1) * 512 + chunk * 8;
    const _Float16* gwb0 = wek + (size_t)(n0 + r0) * 512 + chunk * 8;
    const _Float16* gwb1 = wek + (size_t)(n0 + r1) * 512 + chunk * 8;

    auto stage = [&](int buf, int k0) {
        GLL2(gqa0 + k0, buf * 16384 + tid * 16);
        GLL2(gqa1 + k0, buf * 16384 + 4096 + tid * 16);
        GLL2(gwb0 + k0, buf * 16384 + 8192 + tid * 16);
        GLL2(gwb1 + k0, buf * 16384 + 12288 + tid * 16);
    };

    f32x4 acc[4][4];
    #pragma unroll
    for (int i = 0; i < 4; ++i)
        #pragma unroll
        for (int j = 0; j < 4; ++j)
            acc[i][j] = (f32x4){0.f, 0.f, 0.f, 0.f};

    int swzA = (((wrow >> 6) * 4 + cg) ^ (lx & 7)) * 16;
    int swzB = (((wcol >> 6) * 4 + cg) ^ (lx & 7)) * 16;
    int abase = lx * 128 + swzA;
    int bbase = 8192 + lx * 128 + swzB;

    stage(0, 0);
    __syncthreads();

    #pragma unroll
    for (int ks = 0; ks < 16; ++ks) {
        int p = ks & 1;
        if (ks < 15) stage(p ^ 1, (ks + 1) * 32);
        f16x8 af[4], bf[4];
        #pragma unroll
        for (int i = 0; i < 4; ++i) {
            af[i] = *(const f16x8*)(smem + p * 16384 + abase + i * 2048);
            bf[i] = *(const f16x8*)(smem + p * 16384 + bbase + i * 2048);
        }
        #pragma unroll
        for (int i = 0; i < 4; ++i)
            #pragma unroll
            for (int j = 0; j < 4; ++j)
                acc[i][j] = __builtin_amdgcn_mfma_f32_16x16x32_f16(af[i], bf[j], acc[i][j], 0, 0, 0);
        __syncthreads();
    }

    #pragma unroll
    for (int fi = 0; fi < 4; ++fi) {
        #pragma unroll
        for (int r = 0; r < 4; ++r) {
            float v1 = INFINITY, v2 = INFINITY; int i1 = NCODE, i2 = NCODE;
            #pragma unroll
            for (int fj = 0; fj < 4; ++fj) {
                int nl = wcol + fj * 16 + lx;
                float s = ensh[nl] - 2.0f * acc[fi][fj][r];
                int code = n0 + nl;
                if (s < v1) { v2 = v1; i2 = i1; v1 = s; i1 = code; }
                else if (s < v2) { v2 = s; i2 = code; }
            }
            #pragma unroll
            for (int d = 1; d < 16; d <<= 1) {
                float ov1 = __shfl_xor(v1, d), ov2 = __shfl_xor(v2, d);
                int oi1 = __shfl_xor(i1, d), oi2 = __shfl_xor(i2, d);
                if (ov1 < v1) {
                    if (v1 < ov2) { v2 = v1; i2 = i1; } else { v2 = ov2; i2 = oi2; }
                    v1 = ov1; i1 = oi1;
                } else if (ov1 < v2) { v2 = ov1; i2 = oi1; }
            }
            if (lx == 0) {
                int row = wrow + fi * 16 + cg * 4 + r;
                bb[row * 2 + (wave >> 1)] = make_float4(v1, __int_as_float(i1),
                                                        v2, __int_as_float(i2));
            }
        }
    }
    __syncthreads();
    if (tid < 128) {
        float4 A4 = bb[tid * 2], C4 = bb[tid * 2 + 1];
        float v1, v2; int i1, i2;
        if (A4.x <= C4.x) {
            v1 = A4.x; i1 = __float_as_int(A4.y);
            if (A4.z <= C4.x) { v2 = A4.z; i2 = __float_as_int(A4.w); }
            else { v2 = C4.x; i2 = __float_as_int(C4.y); }
        } else {
            v1 = C4.x; i1 = __float_as_int(C4.y);
            if (C4.z <= A4.x) { v2 = C4.z; i2 = __float_as_int(C4.w); }
            else { v2 = A4.x; i2 = __float_as_int(A4.y); }
        }
        partial[(size_t)(m0 + tid) * 16 + bx] =
            make_uint2(packkey(v1, i1), packkey(v2, i2));
    }
}

// ---------------- rescue: exact fp32 rescore of near-min candidates ----------------
__global__ __launch_bounds__(256) void k_rescue(
        const uint2* __restrict__ partial, const float* __restrict__ qf,
        const float* __restrict__ E, const float* __restrict__ enorm,
        int* __restrict__ idxb, int nslots) {
    int wid = (blockIdx.x * 256 + threadIdx.x) >> 6;   // one wave per query
    int lane = threadIdx.x & 63;
    unsigned k1 = 0xFFFFFFFFu, k2 = 0xFFFFFFFFu;
    if (lane < nslots) {
        uint2 kk = partial[(size_t)wid * nslots + lane];
        k1 = kk.x; k2 = kk.y;
    }
    float v1 = unpk(k1), v2 = unpk(k2);
    float bv = v1;
    #pragma unroll
    for (int d = 1; d < 64; d <<= 1) bv = fminf(bv, __shfl_xor(bv, d));
    float thresh = bv + DELTA;
    unsigned long long m1 = __ballot(lane < nslots && v1 <= thresh);
    unsigned long long m2 = __ballot(lane < nslots && v2 <= thresh);
    const float* q = qf + (size_t)wid * 512 + lane * 8;
    float4 q0 = *(const float4*)q;
    float4 q1 = *(const float4*)(q + 4);
    float w = wseg(lane * 8);                 // segment bounds are multiples of 8
    float qw0 = q0.x * w, qw1 = q0.y * w, qw2 = q0.z * w, qw3 = q0.w * w;
    float qw4 = q1.x * w, qw5 = q1.y * w, qw6 = q1.z * w, qw7 = q1.w * w;
    float bs = INFINITY; int bi = NCODE;
    while (m1 | m2) {
        int ci;
        if (m1) {
            int src = __ffsll((long long)m1) - 1; m1 &= m1 - 1;
            ci = __shfl((int)k1, src) & 2047;
        } else {
            int src = __ffsll((long long)m2) - 1; m2 &= m2 - 1;
            ci = __shfl((int)k2, src) & 2047;
        }
        const float* e = E + (size_t)ci * 512 + lane * 8;
        float4 e0 = *(const float4*)e;
        float4 e1 = *(const float4*)(e + 4);
        float a = 0.f;
        a = fmaf(qw0, e0.x, a); a = fmaf(qw1, e0.y, a);
        a = fmaf(qw2, e0.z, a); a = fmaf(qw3, e0.w, a);
        a = fmaf(qw4, e1.x, a); a = fmaf(qw5, e1.y, a);
        a = fmaf(qw6, e1.z, a); a = fmaf(qw7, e1.w, a);
        #pragma unroll
        for (int d = 1; d < 64; d <<= 1) a += __shfl_xor(a, d);
        float s = enorm[ci] - 2.0f * a;
        if (s < bs || (s == bs && ci < bi)) { bs = s; bi = ci; }
    }
    if (lane == 0) idxb[wid] = bi;
}

// ---------------- fused update (column-split, float2): rest-=up; dacc; emit next q ----------------
__global__ __launch_bounds__(256) void k_update(
        const float* __restrict__ E, const int* __restrict__ idx,
        const float* __restrict__ f, float* __restrict__ rest,
        float* __restrict__ dacc, _Float16* __restrict__ q16n,
        float* __restrict__ qf32n, int pn, int sn, int mode) {
    int t = threadIdx.x;
    int pn_next = 1 << sn;
    int r = 64 >> sn;                        // rows per chunk (1..32)
    int b = blockIdx.x >> sn;
    int chunk = blockIdx.x & (pn_next - 1);
    int lane = t & 63, wave = t >> 6;
    int col = wave * 128 + lane * 2;         // cols {col, col+1}, same wseg segment
    float w0 = wseg(col);
    float macc0 = 0.f, macc1 = 0.f;
    float pscale = (float)pn * (1.0f / 64.0f);
    __shared__ float daccP[32][5];           // [ri][wave], padded
    #pragma unroll 1
    for (int ri = 0; ri < r; ++ri) {
        int n = chunk * r + ri;
        int row = (b << 6) + n;
        float srcp = fminf(fmaxf((n + 0.5f) * pscale - 0.5f, 0.0f), (float)(pn - 1));
        int i0 = (int)floorf(srcp);
        int i1 = min(i0 + 1, pn - 1);
        float wl = srcp - (float)i0;
        int cc0 = idx[b * pn + i0];
        int cc1 = idx[b * pn + i1];
        float2 e0 = *(const float2*)(E + (size_t)cc0 * 512 + col);
        float2 e1 = *(const float2*)(E + (size_t)cc1 * 512 + col);
        size_t off = (size_t)row * 512 + col;
        float2 rv = (mode & 1) ? *(const float2*)(f + off)
                               : *(const float2*)(rest + off);
        float h0 = (1.0f - wl) * e0.x + wl * e1.x;
        float h1 = (1.0f - wl) * e0.y + wl * e1.y;
        float v0 = rv.x - h0, v1 = rv.y - h1;
        float2 wout;
        if (mode & 2) {
            float2 fv = *(const float2*)(f + off);
            wout = make_float2(fv.x - v0, fv.y - v1);
        } else {
            wout = make_float2(v0, v1);
        }
        *(float2*)(rest + off) = wout;
        float s = fmaf(w0 * v0, v0, w0 * v1 * v1);
        #pragma unroll
        for (int d = 1; d < 64; d <<= 1) s += __shfl_xor(s, d);
        if (lane == 0) daccP[ri][wave] = s;
        macc0 += v0; macc1 += v1;
    }
    __syncthreads();
    if (t < r) {
        int row = (b << 6) + chunk * r + t;
        float tot = daccP[t][0] + daccP[t][1] + daccP[t][2] + daccP[t][3];
        dacc[row] = (mode & 1) ? tot : dacc[row] + tot;
    }
    if (!(mode & 2)) {
        float inv = 1.0f / (float)r;
        size_t qrow = ((size_t)b << sn) + chunk;
        float m0v = macc0 * inv, m1v = macc1 * inv;
        q16n[qrow * 512 + col] = (_Float16)m0v;
        q16n[qrow * 512 + col + 1] = (_Float16)m1v;
        if (mode & 4) {
            *(float2*)(qf32n + qrow * 512 + col) = make_float2(m0v, m1v);
        }
    }
}

// ---------------- finalize losses ----------------
__global__ void k_out12(const float* __restrict__ dacc, float* __restrict__ out) {
    int i = blockIdx.x * 256 + threadIdx.x; // 65536
    float d = dacc[i];
    out[i] = d * (0.25f / 7.0f);
    out[BN_ + i] = d * (1.0f / 7.0f);
}

extern "C" void kernel_launch(void* const* d_in, const int* in_sizes, int n_in,
                              void* d_out, int out_size, void* d_ws, size_t ws_size,
                              hipStream_t stream) {
    const float* f    = (const float*)d_in[0];
    const float* base = (const float*)d_in[1];
    const float* W    = (const float*)d_in[2];
    float* out = (float*)d_out;
    float* rest = out;                        // d_out doubles as f_rest

    char* ws = (char*)d_ws;
    float*     E      = (float*)ws;     ws += (size_t)NCODE * 512 * 4;    // 4 MB
    _Float16*  wek16  = (_Float16*)ws;  ws += (size_t)NCODE * 512 * 2;    // 2 MB
    _Float16*  q16a   = (_Float16*)ws;  ws += (size_t)32768 * 512 * 2;    // 32 MB (pn<=32 q16 | pn=64 partial)
    char*      big64  = ws;             ws += (size_t)65536 * 512 * 2;    // 64 MB (qf32 pn<=32 | q16 pn=64)
    uint2*     partS  = (uint2*)ws;     ws += (size_t)32768 * 32 * 8;     // 8 MB (pn<=32 partial)
    float*     dacc   = (float*)ws;     ws += (size_t)BN_ * 4;
    int*       idxb   = (int*)ws;       ws += (size_t)BN_ * 4;
    float*     enorm  = (float*)ws;     ws += (size_t)NCODE * 4;

    k_gemm_e<<<dim3(NCODE / 64, 512 / 64), 256, 0, stream>>>(base, W, E, wek16);
    k_enorm<<<NCODE / 256, 256, 0, stream>>>(E, enorm);
    k_down0<<<B_, 256, 0, stream>>>(f, q16a, (float*)big64);

    const int scales[7] = {1, 2, 4, 8, 16, 32, 64};
    for (int si = 0; si < 7; ++si) {
        int pn = scales[si];
        int M = 1024 * pn;
        const _Float16* q16s = (pn == 64) ? (const _Float16*)big64 : q16a;
        const float*    qfs  = (pn == 64) ? rest : (const float*)big64;

        if (pn >= 8) {
            uint2* part = (pn == 64) ? (uint2*)q16a : partS;
            k_score_256<<<8 * (M / 256), 512, 65536, stream>>>(q16s, wek16, enorm, part);
            k_rescue<<<M / 4, 256, 0, stream>>>(part, qfs, E, enorm, idxb, 32);
        } else {
            k_score_f16<<<16 * (M / 128), 256, 0, stream>>>(q16s, wek16, enorm, partS);
            k_rescue<<<M / 4, 256, 0, stream>>>(partS, qfs, E, enorm, idxb, 16);
        }

        int pn_next = (si == 6) ? 64 : pn * 2;
        int sn = 0; while ((1 << sn) != pn_next) ++sn;
        int mode = (si == 0 ? 1 : 0) | (si == 6 ? 2 : 0) | ((si <= 4) ? 4 : 0);
        _Float16* q16n = (pn_next == 64) ? (_Float16*)big64 : q16a;
        k_update<<<1024 * pn_next, 256, 0, stream>>>(E, idxb, f, rest, dacc,
                                                     q16n, (float*)big64, pn, sn, mode);
    }

    k_out12<<<BN_ / 256, 256, 0, stream>>>(dacc, out + NTOT);
}

// Round 15
// 969.703 us; speedup vs baseline: 1.0324x; 1.0324x over previous
//
#include <hip/hip_runtime.h>

typedef __attribute__((ext_vector_type(8))) _Float16 f16x8;
typedef __attribute__((ext_vector_type(4))) float f32x4;

#define B_    1024
#define C_    512
#define NCODE 2048
#define NTOT  (B_ * 64 * C_)   // 33,554,432
#define BN_   (B_ * 64)        // 65,536
#define DELTA 6e-3f

__device__ __forceinline__ float wseg(int k) {
    return k < 256 ? (1.0f / 256.0f) : (k < 384 ? (1.0f / 128.0f) : (1.0f / 64.0f));
}

// sortable-key helpers: ascending float -> ascending uint; low 11 bits replaced by code idx
__device__ __forceinline__ unsigned packkey(float s, int code) {
    unsigned u = __float_as_uint(s);
    u = (u & 0x80000000u) ? ~u : (u | 0x80000000u);
    return (u & 0xFFFFF800u) | (unsigned)code;
}
__device__ __forceinline__ float unpk(unsigned k) {
    unsigned us = k & 0xFFFFF800u;
    return (us & 0x80000000u) ? __uint_as_float(us ^ 0x80000000u) : __uint_as_float(~us);
}

// ---------------- E = base @ W^T  (+ fused f16 weighted copy) ----------------
__global__ __launch_bounds__(256) void k_gemm_e(const float* __restrict__ A,
                                                const float* __restrict__ Bm,
                                                float* __restrict__ E,
                                                _Float16* __restrict__ wk) {
    __shared__ float As[16][68];
    __shared__ float Bs[16][68];
    int tid = threadIdx.x;
    int m0 = blockIdx.x * 64, n0 = blockIdx.y * 64;
    float acc[4][4] = {};
    int tx = tid & 15, ty = tid >> 4;
    int kk = tid & 15, rr = tid >> 4;
    for (int k0 = 0; k0 < 512; k0 += 16) {
        #pragma unroll
        for (int i = 0; i < 4; ++i) {
            As[kk][rr + i * 16] = A[(m0 + rr + i * 16) * 512 + k0 + kk];
            Bs[kk][rr + i * 16] = Bm[(n0 + rr + i * 16) * 512 + k0 + kk];
        }
        __syncthreads();
        #pragma unroll
        for (int k = 0; k < 16; ++k) {
            float4 a = *(const float4*)&As[k][ty * 4];
            float4 b = *(const float4*)&Bs[k][tx * 4];
            #pragma unroll
            for (int i = 0; i < 4; ++i) {
                float av = ((const float*)&a)[i];
                acc[i][0] = fmaf(av, b.x, acc[i][0]);
                acc[i][1] = fmaf(av, b.y, acc[i][1]);
                acc[i][2] = fmaf(av, b.z, acc[i][2]);
                acc[i][3] = fmaf(av, b.w, acc[i][3]);
            }
        }
        __syncthreads();
    }
    #pragma unroll
    for (int i = 0; i < 4; ++i)
        #pragma unroll
        for (int j = 0; j < 4; ++j) {
            int cc = m0 + ty * 4 + i;       // code index
            int kx = n0 + tx * 4 + j;       // k index
            float v = acc[i][j];
            E[cc * 512 + kx] = v;
            wk[cc * 512 + kx] = (_Float16)(v * wseg(kx));   // w = 2^-s, exact scale
        }
}

// ---------------- enorm[c] = sum_k wseg(k)*E[c][k]^2 (one wave per code) ----------------
__global__ __launch_bounds__(256) void k_enorm(const float* __restrict__ E,
                                               float* __restrict__ enorm) {
    int wid = (blockIdx.x * 256 + threadIdx.x) >> 6;   // code index (2048 waves)
    int lane = threadIdx.x & 63;
    const float* e = E + (size_t)wid * 512 + lane * 8;
    float4 e0 = *(const float4*)e;
    float4 e1 = *(const float4*)(e + 4);
    float w = wseg(lane * 8);           // segment bounds are multiples of 8
    float s = 0.f;
    s = fmaf(e0.x, e0.x, s); s = fmaf(e0.y, e0.y, s);
    s = fmaf(e0.z, e0.z, s); s = fmaf(e0.w, e0.w, s);
    s = fmaf(e1.x, e1.x, s); s = fmaf(e1.y, e1.y, s);
    s = fmaf(e1.z, e1.z, s); s = fmaf(e1.w, e1.w, s);
    s *= w;
    #pragma unroll
    for (int d = 1; d < 64; d <<= 1) s += __shfl_xor(s, d);
    if (lane == 0) enorm[wid] = s;
}

// ---------------- initial downsample (pn=1): q = mean_n f ----------------
__global__ __launch_bounds__(256) void k_down0(const float* __restrict__ f,
                                               _Float16* __restrict__ q16,
                                               float* __restrict__ qf) {
    int b = blockIdx.x, t = threadIdx.x;
    const float* src = f + (size_t)b * 64 * 512;
    float s0 = 0.f, s1 = 0.f;
    for (int n = 0; n < 64; ++n) {
        s0 += src[n * 512 + t];
        s1 += src[n * 512 + t + 256];
    }
    s0 *= (1.0f / 64.0f); s1 *= (1.0f / 64.0f);
    q16[(size_t)b * 512 + t] = (_Float16)s0;
    q16[(size_t)b * 512 + t + 256] = (_Float16)s1;
    qf[(size_t)b * 512 + t] = s0;
    qf[(size_t)b * 512 + t + 256] = s1;
}

// ================= 256x256 MFMA score kernel, BK=32 x 4 buffers, 1 barrier/tile =================
// (round-12/13 measured-best structure: counted vmcnt(8), interleaved reads)
#define GLL2(gp, loff) __builtin_amdgcn_global_load_lds( \
    (const __attribute__((address_space(1))) unsigned int*)(gp), \
    (__attribute__((address_space(3))) unsigned int*)(smem + (loff)), 16, 0, 0)

__global__ __launch_bounds__(512, 2) void k_score_256(
        const _Float16* __restrict__ q16, const _Float16* __restrict__ wek,
        const float* __restrict__ enorm, uint2* __restrict__ partial) {
    extern __shared__ char smem[];     // 131072 B
    int tid = threadIdx.x;
    int x = blockIdx.x;
    int bx = (x >> 3) & 7;                       // 8 col tiles of 256
    int g  = (x & 7) + ((x >> 6) << 3);          // row-group, XCD-chunked
    int m0 = g * 256, n0 = bx * 256;

    int lane = tid & 63, wave = tid >> 6;
    int wm = wave >> 2, wn = wave & 3;
    int lx = lane & 15, cg = lane >> 4;

    // ---- staging precompute (cell -> logical row/chunk, bijective XOR) ----
    int r2s = tid >> 3, sl = tid & 7;
    int us = sl ^ (r2s & 7);
    int cs = us & 3;
    int rws = r2s + ((us >> 2) << 6);            // 0..127 within region rows
    const _Float16* srcA0 = q16 + (size_t)(m0 + rws) * 512 + cs * 8;
    const _Float16* srcA1 = q16 + (size_t)(m0 + 128 + rws) * 512 + cs * 8;
    const _Float16* srcB0 = wek + (size_t)(n0 + rws) * 512 + cs * 8;
    const _Float16* srcB1 = wek + (size_t)(n0 + 128 + rws) * 512 + cs * 8;

    #define STG_A2(BUF, KT) { \
        GLL2(srcA0 + (KT) * 32, (BUF) * 32768 + tid * 16); \
        GLL2(srcA1 + (KT) * 32, (BUF) * 32768 + 8192 + tid * 16); }
    #define STG_B2(BUF, KT) { \
        GLL2(srcB0 + (KT) * 32, (BUF) * 32768 + 16384 + tid * 16); \
        GLL2(srcB1 + (KT) * 32, (BUF) * 32768 + 24576 + tid * 16); }

    // ---- fragment read offsets (bytes within a 32KB buffer) ----
    int Aoff[8];
    #pragma unroll
    for (int fi = 0; fi < 8; ++fi) {
        int rA = fi * 16 + lx;                   // 0..127 within rh = wm
        Aoff[fi] = wm * 8192 + (rA & 63) * 128 +
                   (((((rA >> 6) & 1) << 2) + cg) ^ (rA & 7)) * 16;
    }
    int Boff[4];
    #pragma unroll
    for (int fj = 0; fj < 4; ++fj) {
        int br = wn * 64 + fj * 16 + lx;         // 0..255
        int rB = br & 127;
        Boff[fj] = 16384 + (br >> 7) * 8192 + (rB & 63) * 128 +
                   (((((rB >> 6) & 1) << 2) + cg) ^ (rB & 7)) * 16;
    }

    f32x4 acc[8][4];
    #pragma unroll
    for (int i = 0; i < 8; ++i)
        #pragma unroll
        for (int j = 0; j < 4; ++j)
            acc[i][j] = (f32x4){0.f, 0.f, 0.f, 0.f};

    #define MF(a, b, c) __builtin_amdgcn_mfma_f32_16x16x32_f16(a, b, c, 0, 0, 0)

    // ---- prologue: stage tiles 0,1,2 (12 loads in flight) ----
    STG_A2(0, 0); STG_B2(0, 0);
    STG_A2(1, 1); STG_B2(1, 1);
    STG_A2(2, 2); STG_B2(2, 2);

    // ---- K loop: 16 tiles, ONE barrier per tile; reads interleaved with MFMA rows ----
    #pragma unroll
    for (int t = 0; t < 16; ++t) {
        const int buf = (t & 3) * 32768;
        const int sb = (t + 3) & 3;
        // own tile-t stage landed (counted; 8 = tiles t+1,t+2 stay in flight)
        if (t <= 13)      { asm volatile("s_waitcnt vmcnt(8)" ::: "memory"); }
        else if (t == 14) { asm volatile("s_waitcnt vmcnt(4)" ::: "memory"); }
        else              { asm volatile("s_waitcnt vmcnt(0)" ::: "memory"); }
        __builtin_amdgcn_s_barrier();            // all waves' tile-t stage landed
        __builtin_amdgcn_sched_barrier(0);       // pin reads below the barrier
        f16x8 b0 = *(const f16x8*)(smem + buf + Boff[0]);
        f16x8 b1 = *(const f16x8*)(smem + buf + Boff[1]);
        f16x8 b2 = *(const f16x8*)(smem + buf + Boff[2]);
        f16x8 b3 = *(const f16x8*)(smem + buf + Boff[3]);
        f16x8 a0 = *(const f16x8*)(smem + buf + Aoff[0]);
        __builtin_amdgcn_s_setprio(1);
        acc[0][0] = MF(a0, b0, acc[0][0]); acc[0][1] = MF(a0, b1, acc[0][1]);
        acc[0][2] = MF(a0, b2, acc[0][2]); acc[0][3] = MF(a0, b3, acc[0][3]);
        f16x8 a1 = *(const f16x8*)(smem + buf + Aoff[1]);
        acc[1][0] = MF(a1, b0, acc[1][0]); acc[1][1] = MF(a1, b1, acc[1][1]);
        acc[1][2] = MF(a1, b2, acc[1][2]); acc[1][3] = MF(a1, b3, acc[1][3]);
        f16x8 a2 = *(const f16x8*)(smem + buf + Aoff[2]);
        acc[2][0] = MF(a2, b0, acc[2][0]); acc[2][1] = MF(a2, b1, acc[2][1]);
        acc[2][2] = MF(a2, b2, acc[2][2]); acc[2][3] = MF(a2, b3, acc[2][3]);
        f16x8 a3 = *(const f16x8*)(smem + buf + Aoff[3]);
        acc[3][0] = MF(a3, b0, acc[3][0]); acc[3][1] = MF(a3, b1, acc[3][1]);
        acc[3][2] = MF(a3, b2, acc[3][2]); acc[3][3] = MF(a3, b3, acc[3][3]);
        if (t < 13) { STG_A2(sb, t + 3); STG_B2(sb, t + 3); }
        f16x8 a4 = *(const f16x8*)(smem + buf + Aoff[4]);
        acc[4][0] = MF(a4, b0, acc[4][0]); acc[4][1] = MF(a4, b1, acc[4][1]);
        acc[4][2] = MF(a4, b2, acc[4][2]); acc[4][3] = MF(a4, b3, acc[4][3]);
        f16x8 a5 = *(const f16x8*)(smem + buf + Aoff[5]);
        acc[5][0] = MF(a5, b0, acc[5][0]); acc[5][1] = MF(a5, b1, acc[5][1]);
        acc[5][2] = MF(a5, b2, acc[5][2]); acc[5][3] = MF(a5, b3, acc[5][3]);
        f16x8 a6 = *(const f16x8*)(smem + buf + Aoff[6]);
        acc[6][0] = MF(a6, b0, acc[6][0]); acc[6][1] = MF(a6, b1, acc[6][1]);
        acc[6][2] = MF(a6, b2, acc[6][2]); acc[6][3] = MF(a6, b3, acc[6][3]);
        f16x8 a7 = *(const f16x8*)(smem + buf + Aoff[7]);
        acc[7][0] = MF(a7, b0, acc[7][0]); acc[7][1] = MF(a7, b1, acc[7][1]);
        acc[7][2] = MF(a7, b2, acc[7][2]); acc[7][3] = MF(a7, b3, acc[7][3]);
        __builtin_amdgcn_s_setprio(0);
    }

    // ---- epilogue pass 1: per-lane fj-fold best2 -> packed keys -> smem ----
    __syncthreads();
    float en[4];
    #pragma unroll
    for (int fj = 0; fj < 4; ++fj) en[fj] = enorm[n0 + wn * 64 + fj * 16 + lx];

    #pragma unroll
    for (int fi = 0; fi < 8; ++fi) {
        #pragma unroll
        for (int rr = 0; rr < 4; ++rr) {
            unsigned a1 = 0xFFFFFFFFu, a2 = 0xFFFFFFFFu;
            #pragma unroll
            for (int fj = 0; fj < 4; ++fj) {
                float s = fmaf(-2.0f, acc[fi][fj][rr], en[fj]);
                unsigned key = packkey(s, n0 + wn * 64 + fj * 16 + lx);
                if (key < a1) { a2 = a1; a1 = key; }
                else if (key < a2) a2 = key;
            }
            int row_local = wm * 128 + fi * 16 + cg * 4 + rr;
            int task = row_local * 4 + wn;
            *(uint2*)(smem + task * 128 + ((lx ^ (task & 15)) * 8)) = make_uint2(a1, a2);
        }
    }
    __syncthreads();
    // ---- epilogue pass 2: 1024 tasks, merge 16 sorted pairs each ----
    #pragma unroll
    for (int rep = 0; rep < 2; ++rep) {
        int task = tid + rep * 512;
        unsigned a1 = 0xFFFFFFFFu, a2 = 0xFFFFFFFFu;
        #pragma unroll
        for (int j = 0; j < 16; ++j) {
            uint2 pr = *(const uint2*)(smem + task * 128 + (((j ^ (task & 15))) * 8));
            if (pr.x < a1) { a2 = min(a1, pr.y); a1 = pr.x; }
            else a2 = min(a2, pr.x);
        }
        int row = m0 + (task >> 2);
        partial[(size_t)row * 32 + (bx * 4 + (task & 3))] = make_uint2(a1, a2);
    }
    #undef STG_A2
    #undef STG_B2
    #undef MF
}

// ---------------- 128x128 score kernel (r6 structure; used for pn <= 4) ----------------
__global__ __launch_bounds__(256) void k_score_f16(
        const _Float16* __restrict__ q16, const _Float16* __restrict__ wek,
        const float* __restrict__ enorm, uint2* __restrict__ partial) {
    __shared__ __align__(16) char smem[37376];
    float*  ensh = (float*)(smem + 32768);
    float4* bb   = (float4*)(smem + 33280);

    int tid = threadIdx.x;
    int x = blockIdx.x;
    int bx = (x >> 3) & 15;
    int g  = (x & 7) + ((x >> 7) << 3);
    int m0 = g * 128, n0 = bx * 128;
    if (tid < 128) ensh[tid] = enorm[n0 + tid];

    int lane = tid & 63, wave = tid >> 6;
    int wrow = (wave & 1) * 64, wcol = (wave >> 1) * 64;
    int lx = lane & 15, cg = lane >> 4;

    int u = (tid & 7) ^ ((tid >> 3) & 7);
    int chunk = u & 3;
    int rhi = (u >> 2) << 6;
    int r0 = (tid >> 3) + rhi;
    int r1 = 32 + (tid >> 3) + rhi;
    const _Float16* gqa0 = q16 + (size_t)(m0 + r0) * 512 + chunk * 8;
    const _Float16* gqa1 = q16 + (size_t)(m0 + r1) * 512 + chunk * 8;
    const _Float16* gwb0 = wek + (size_t)(n0 + r0) * 512 + chunk * 8;
    const _Float16* gwb1 = wek + (size_t)(n0 + r1) * 512 + chunk * 8;

    auto stage = [&](int buf, int k0) {
        GLL2(gqa0 + k0, buf * 16384 + tid * 16);
        GLL2(gqa1 + k0, buf * 16384 + 4096 + tid * 16);
        GLL2(gwb0 + k0, buf * 16384 + 8192 + tid * 16);
        GLL2(gwb1 + k0, buf * 16384 + 12288 + tid * 16);
    };

    f32x4 acc[4][4];
    #pragma unroll
    for (int i = 0; i < 4; ++i)
        #pragma unroll
        for (int j = 0; j < 4; ++j)
            acc[i][j] = (f32x4){0.f, 0.f, 0.f, 0.f};

    int swzA = (((wrow >> 6) * 4 + cg) ^ (lx & 7)) * 16;
    int swzB = (((wcol >> 6) * 4 + cg) ^ (lx & 7)) * 16;
    int abase = lx * 128 + swzA;
    int bbase = 8192 + lx * 128 + swzB;

    stage(0, 0);
    __syncthreads();

    #pragma unroll
    for (int ks = 0; ks < 16; ++ks) {
        int p = ks & 1;
        if (ks < 15) stage(p ^ 1, (ks + 1) * 32);
        f16x8 af[4], bf[4];
        #pragma unroll
        for (int i = 0; i < 4; ++i) {
            af[i] = *(const f16x8*)(smem + p * 16384 + abase + i * 2048);
            bf[i] = *(const f16x8*)(smem + p * 16384 + bbase + i * 2048);
        }
        #pragma unroll
        for (int i = 0; i < 4; ++i)
            #pragma unroll
            for (int j = 0; j < 4; ++j)
                acc[i][j] = __builtin_amdgcn_mfma_f32_16x16x32_f16(af[i], bf[j], acc[i][j], 0, 0, 0);
        __syncthreads();
    }

    #pragma unroll
    for (int fi = 0; fi < 4; ++fi) {
        #pragma unroll
        for (int r = 0; r < 4; ++r) {
            float v1 = INFINITY, v2 = INFINITY; int i1 = NCODE, i2 = NCODE;
            #pragma unroll
            for (int fj = 0; fj < 4; ++fj) {
                int nl = wcol + fj * 16 + lx;
                float s = ensh[nl] - 2.0f * acc[fi][fj][r];
                int code = n0 + nl;
                if (s < v1) { v2 = v1; i2 = i1; v1 = s; i1 = code; }
                else if (s < v2) { v2 = s; i2 = code; }
            }
            #pragma unroll
            for (int d = 1; d < 16; d <<= 1) {
                float ov1 = __shfl_xor(v1, d), ov2 = __shfl_xor(v2, d);
                int oi1 = __shfl_xor(i1, d), oi2 = __shfl_xor(i2, d);
                if (ov1 < v1) {
                    if (v1 < ov2) { v2 = v1; i2 = i1; } else { v2 = ov2; i2 = oi2; }
                    v1 = ov1; i1 = oi1;
                } else if (ov1 < v2) { v2 = ov1; i2 = oi1; }
            }
            if (lx == 0) {
                int row = wrow + fi * 16 + cg * 4 + r;
                bb[row * 2 + (wave >> 1)] = make_float4(v1, __int_as_float(i1),
                                                        v2, __int_as_float(i2));
            }
        }
    }
    __syncthreads();
    if (tid < 128) {
        float4 A4 = bb[tid * 2], C4 = bb[tid * 2 + 1];
        float v1, v2; int i1, i2;
        if (A4.x <= C4.x) {
            v1 = A4.x; i1 = __float_as_int(A4.y);
            if (A4.z <= C4.x) { v2 = A4.z; i2 = __float_as_int(A4.w); }
            else { v2 = C4.x; i2 = __float_as_int(C4.y); }
        } else {
            v1 = C4.x; i1 = __float_as_int(C4.y);
            if (C4.z <= A4.x) { v2 = C4.z; i2 = __float_as_int(C4.w); }
            else { v2 = A4.x; i2 = __float_as_int(A4.y); }
        }
        partial[(size_t)(m0 + tid) * 16 + bx] =
            make_uint2(packkey(v1, i1), packkey(v2, i2));
    }
}

// ---------------- rescue: exact fp32 rescore of near-min candidates ----------------
__global__ __launch_bounds__(256) void k_rescue(
        const uint2* __restrict__ partial, const float* __restrict__ qf,
        const float* __restrict__ E, const float* __restrict__ enorm,
        int* __restrict__ idxb, int nslots) {
    int wid = (blockIdx.x * 256 + threadIdx.x) >> 6;   // one wave per query
    int lane = threadIdx.x & 63;
    unsigned k1 = 0xFFFFFFFFu, k2 = 0xFFFFFFFFu;
    if (lane < nslots) {
        uint2 kk = partial[(size_t)wid * nslots + lane];
        k1 = kk.x; k2 = kk.y;
    }
    float v1 = unpk(k1), v2 = unpk(k2);
    float bv = v1;
    #pragma unroll
    for (int d = 1; d < 64; d <<= 1) bv = fminf(bv, __shfl_xor(bv, d));
    float thresh = bv + DELTA;
    unsigned long long m1 = __ballot(lane < nslots && v1 <= thresh);
    unsigned long long m2 = __ballot(lane < nslots && v2 <= thresh);
    const float* q = qf + (size_t)wid * 512 + lane * 8;
    float4 q0 = *(const float4*)q;
    float4 q1 = *(const float4*)(q + 4);
    float w = wseg(lane * 8);                 // segment bounds are multiples of 8
    float qw0 = q0.x * w, qw1 = q0.y * w, qw2 = q0.z * w, qw3 = q0.w * w;
    float qw4 = q1.x * w, qw5 = q1.y * w, qw6 = q1.z * w, qw7 = q1.w * w;
    float bs = INFINITY; int bi = NCODE;
    while (m1 | m2) {
        int ci;
        if (m1) {
            int src = __ffsll((long long)m1) - 1; m1 &= m1 - 1;
            ci = __shfl((int)k1, src) & 2047;
        } else {
            int src = __ffsll((long long)m2) - 1; m2 &= m2 - 1;
            ci = __shfl((int)k2, src) & 2047;
        }
        const float* e = E + (size_t)ci * 512 + lane * 8;
        float4 e0 = *(const float4*)e;
        float4 e1 = *(const float4*)(e + 4);
        float a = 0.f;
        a = fmaf(qw0, e0.x, a); a = fmaf(qw1, e0.y, a);
        a = fmaf(qw2, e0.z, a); a = fmaf(qw3, e0.w, a);
        a = fmaf(qw4, e1.x, a); a = fmaf(qw5, e1.y, a);
        a = fmaf(qw6, e1.z, a); a = fmaf(qw7, e1.w, a);
        #pragma unroll
        for (int d = 1; d < 64; d <<= 1) a += __shfl_xor(a, d);
        float s = enorm[ci] - 2.0f * a;
        if (s < bs || (s == bs && ci < bi)) { bs = s; bi = ci; }
    }
    if (lane == 0) idxb[wid] = bi;
}

// ---------------- fused update (column-split, float2): rest-=up; dacc; emit next q ----------------
__global__ __launch_bounds__(256) void k_update(
        const float* __restrict__ E, const int* __restrict__ idx,
        const float* __restrict__ f, float* __restrict__ rest,
        float* __restrict__ dacc, _Float16* __restrict__ q16n,
        float* __restrict__ qf32n, int pn, int sn, int mode) {
    int t = threadIdx.x;
    int pn_next = 1 << sn;
    int r = 64 >> sn;                        // rows per chunk (1..32)
    int b = blockIdx.x >> sn;
    int chunk = blockIdx.x & (pn_next - 1);
    int lane = t & 63, wave = t >> 6;
    int col = wave * 128 + lane * 2;         // cols {col, col+1}, same wseg segment
    float w0 = wseg(col);
    float macc0 = 0.f, macc1 = 0.f;
    float pscale = (float)pn * (1.0f / 64.0f);
    __shared__ float daccP[32][5];           // [ri][wave], padded
    #pragma unroll 1
    for (int ri = 0; ri < r; ++ri) {
        int n = chunk * r + ri;
        int row = (b << 6) + n;
        float srcp = fminf(fmaxf((n + 0.5f) * pscale - 0.5f, 0.0f), (float)(pn - 1));
        int i0 = (int)floorf(srcp);
        int i1 = min(i0 + 1, pn - 1);
        float wl = srcp - (float)i0;
        int cc0 = idx[b * pn + i0];
        int cc1 = idx[b * pn + i1];
        float2 e0 = *(const float2*)(E + (size_t)cc0 * 512 + col);
        float2 e1 = *(const float2*)(E + (size_t)cc1 * 512 + col);
        size_t off = (size_t)row * 512 + col;
        float2 rv = (mode & 1) ? *(const float2*)(f + off)
                               : *(const float2*)(rest + off);
        float h0 = (1.0f - wl) * e0.x + wl * e1.x;
        float h1 = (1.0f - wl) * e0.y + wl * e1.y;
        float v0 = rv.x - h0, v1 = rv.y - h1;
        float2 wout;
        if (mode & 2) {
            float2 fv = *(const float2*)(f + off);
            wout = make_float2(fv.x - v0, fv.y - v1);
        } else {
            wout = make_float2(v0, v1);
        }
        *(float2*)(rest + off) = wout;
        float s = fmaf(w0 * v0, v0, w0 * v1 * v1);
        #pragma unroll
        for (int d = 1; d < 64; d <<= 1) s += __shfl_xor(s, d);
        if (lane == 0) daccP[ri][wave] = s;
        macc0 += v0; macc1 += v1;
    }
    __syncthreads();
    if (t < r) {
        int row = (b << 6) + chunk * r + t;
        float tot = daccP[t][0] + daccP[t][1] + daccP[t][2] + daccP[t][3];
        dacc[row] = (mode & 1) ? tot : dacc[row] + tot;
    }
    if (!(mode & 2)) {
        float inv = 1.0f / (float)r;
        size_t qrow = ((size_t)b << sn) + chunk;
        float m0v = macc0 * inv, m1v = macc1 * inv;
        q16n[qrow * 512 + col] = (_Float16)m0v;
        q16n[qrow * 512 + col + 1] = (_Float16)m1v;
        if (mode & 4) {
            *(float2*)(qf32n + qrow * 512 + col) = make_float2(m0v, m1v);
        }
    }
}

// ---------------- finalize losses ----------------
__global__ void k_out12(const float* __restrict__ dacc, float* __restrict__ out) {
    int i = blockIdx.x * 256 + threadIdx.x; // 65536
    float d = dacc[i];
    out[i] = d * (0.25f / 7.0f);
    out[BN_ + i] = d * (1.0f / 7.0f);
}

extern "C" void kernel_launch(void* const* d_in, const int* in_sizes, int n_in,
                              void* d_out, int out_size, void* d_ws, size_t ws_size,
                              hipStream_t stream) {
    const float* f    = (const float*)d_in[0];
    const float* base = (const float*)d_in[1];
    const float* W    = (const float*)d_in[2];
    float* out = (float*)d_out;
    float* rest = out;                        // d_out doubles as f_rest

    char* ws = (char*)d_ws;
    float*     E      = (float*)ws;     ws += (size_t)NCODE * 512 * 4;    // 4 MB
    _Float16*  wek16  = (_Float16*)ws;  ws += (size_t)NCODE * 512 * 2;    // 2 MB
    _Float16*  q16a   = (_Float16*)ws;  ws += (size_t)32768 * 512 * 2;    // 32 MB (pn<=32 q16 | pn=64 partial)
    char*      big64  = ws;             ws += (size_t)65536 * 512 * 2;    // 64 MB (qf32 pn<=32 | q16 pn=64)
    uint2*     partS  = (uint2*)ws;     ws += (size_t)32768 * 32 * 8;     // 8 MB (pn<=32 partial)
    float*     dacc   = (float*)ws;     ws += (size_t)BN_ * 4;
    int*       idxb   = (int*)ws;       ws += (size_t)BN_ * 4;
    float*     enorm  = (float*)ws;     ws += (size_t)NCODE * 4;

    k_gemm_e<<<dim3(NCODE / 64, 512 / 64), 256, 0, stream>>>(base, W, E, wek16);
    k_enorm<<<NCODE / 4, 256, 0, stream>>>(E, enorm);
    k_down0<<<B_, 256, 0, stream>>>(f, q16a, (float*)big64);

    const int scales[7] = {1, 2, 4, 8, 16, 32, 64};
    for (int si = 0; si < 7; ++si) {
        int pn = scales[si];
        int M = 1024 * pn;
        const _Float16* q16s = (pn == 64) ? (const _Float16*)big64 : q16a;
        const float*    qfs  = (pn == 64) ? rest : (const float*)big64;

        if (pn >= 8) {
            uint2* part = (pn == 64) ? (uint2*)q16a : partS;
            k_score_256<<<8 * (M / 256), 512, 131072, stream>>>(q16s, wek16, enorm, part);
            k_rescue<<<M / 4, 256, 0, stream>>>(part, qfs, E, enorm, idxb, 32);
        } else {
            k_score_f16<<<16 * (M / 128), 256, 0, stream>>>(q16s, wek16, enorm, partS);
            k_rescue<<<M / 4, 256, 0, stream>>>(partS, qfs, E, enorm, idxb, 16);
        }

        int pn_next = (si == 6) ? 64 : pn * 2;
        int sn = 0; while ((1 << sn) != pn_next) ++sn;
        int mode = (si == 0 ? 1 : 0) | (si == 6 ? 2 : 0) | ((si <= 4) ? 4 : 0);
        _Float16* q16n = (pn_next == 64) ? (_Float16*)big64 : q16a;
        k_update<<<1024 * pn_next, 256, 0, stream>>>(E, idxb, f, rest, dacc,
                                                     q16n, (float*)big64, pn, sn, mode);
    }

    k_out12<<<BN_ / 256, 256, 0, stream>>>(dacc, out + NTOT);
}